// Round 16
// baseline (152.805 us; speedup 1.0000x reference)
//
#include <hip/hip_runtime.h>

// MonarchLinear: x[16384,256] fp32, L[68,68,68], R[68,68,68], bias[4608] -> out[16384,4608] fp32.
//   t1[b,r,l] = sum_p x[b, r*68+p] * L[r,l,p]           (r<4; r==3 only p<52 valid)
//   out[b, s*68+l] = sum_{r<4} t1[b,r,l] * R[l,s,r] + bias[s*68+l]
//
// Round 16: QUARTER-TILE A/B PIPELINE. r15's big A-restructure changed nothing
// (91.34 vs 91.38) -> A internals not critical. r14's 3.5TB/s avg + ideal WRITE
// = bimodal timeline: grid 1024 = all-resident lockstep cohort, so total =
// T_A + T_B with HBM idle during A. Fix: 4-token quarters; B(q) store-drain
// overlaps A(q+1) compute (stores are fire-and-forget). 5 barriers, disjoint
// t1s quarters. A: tok(2b)|combo(4b)|liq(2b) mapping, 17 li = 5+4+4+4.

typedef float f4 __attribute__((ext_vector_type(4)));

namespace {
constexpr int MM    = 68;
constexpr int IN_D  = 256;
constexpr int OUT_D = 4608;
constexpr int TT    = 16;              // tokens per block
constexpr int QT    = 4;               // tokens per quarter
constexpr int NTH   = 256;
constexpr int NJ    = 5;
constexpr int XROW  = IN_D + 4;        // 260 floats: x row stride in LDS
constexpr int TPAD  = 4 * MM + 4;      // 276 floats: t1 row stride
}

// A dot worker: NLI compile-time (acc/Lv in regs), p4max runtime (no divergence).
template <int NLI>
__device__ __forceinline__ void dotA(const float* __restrict__ xls,
                                     const float* __restrict__ Lrow0,
                                     float* __restrict__ t1w, int p4m)
{
  float acc[NLI];
#pragma unroll
  for (int li = 0; li < NLI; ++li) acc[li] = 0.f;

#pragma unroll 1
  for (int p4 = 0; p4 < p4m; ++p4) {
    f4 xv = *(const f4*)(xls + 4 * p4);            // LDS broadcast
    f4 Lv[NLI];
#pragma unroll
    for (int li = 0; li < NLI; ++li)               // independent L2-hot loads
      Lv[li] = *(const f4*)(Lrow0 + (size_t)li * MM + 4 * p4);
#pragma unroll
    for (int li = 0; li < NLI; ++li) {
      acc[li] = fmaf(xv.x, Lv[li].x, acc[li]);
      acc[li] = fmaf(xv.y, Lv[li].y, acc[li]);
      acc[li] = fmaf(xv.z, Lv[li].z, acc[li]);
      acc[li] = fmaf(xv.w, Lv[li].w, acc[li]);
    }
  }
#pragma unroll
  for (int li = 0; li < NLI; ++li) t1w[li] = acc[li];
}

__global__ __launch_bounds__(NTH, 4)
void monarch_pipe(const float* __restrict__ x, const float* __restrict__ L,
                  const float* __restrict__ R, const float* __restrict__ bias,
                  float* __restrict__ out)
{
  __shared__ float xs[TT * XROW];        // 16,640 B
  __shared__ float t1s[TT * TPAD];       // 17,664 B
  const int tid = threadIdx.x;
  const long tb = (long)blockIdx.x * TT;

  // ---- stage x -> LDS (coalesced, all 16 tokens) ----
#pragma unroll
  for (int k = 0; k < (TT * IN_D / 4) / NTH; ++k) {
    int i   = k * NTH + tid;
    int tok = i >> 6;
    int pos = i & 63;
    *(f4*)(&xs[tok * XROW + 4 * pos]) = *(const f4*)(x + (tb + tok) * IN_D + 4 * pos);
  }

  // ---- A-quarter thread mapping: tok(2b) | combo(4b) | liq(2b) ----
  const int atok = tid & 3;
  const int acb  = (tid >> 2) & 15;
  const int ar   = acb >> 2;
  const int alq  = acb & 3;
  const int liq  = tid >> 6;                       // wave-uniform
  const int li0  = (liq == 0) ? 0 : (4 * liq + 1); // 0,5,9,13
  const int ap4m = (ar == 3) ? 13 : 17;            // runtime trip count, no divergence
  const float* axls = &xs[atok * XROW + ar * MM];  // +4q*XROW per quarter
  const float* aL0  = L + (size_t)(ar * MM + alq * 17 + li0) * MM;
  float*       at1w = &t1s[atok * TPAD + ar * MM + alq * 17 + li0];

  // ---- B thread mapping (r7/8 proven body) ----
  const int g  = tid / 17;
  const int m  = tid - g * 17;
  const int l4 = 4 * m;

  __syncthreads();                                 // xs ready

  // A(q=0)
  if (liq == 0) dotA<5>(axls, aL0, at1w, ap4m);
  else          dotA<4>(axls, aL0, at1w, ap4m);
  __syncthreads();                                 // quarter 0 t1 ready

#pragma unroll 1
  for (int q = 0; q < TT / QT; ++q) {
    // ---- B(q): tokens 4q..4q+3 ----
#pragma unroll 1
    for (int j = 0; j < NJ; ++j) {
      const int s = g + 15 * j;
      // tid==255 duplicates (g=0,j+1); s==67 row has only 52 cols (m<13)
      const bool act = (tid < 255) && (s < MM) && (s < MM - 1 || m < 13);
      const int scol = s * MM + l4;
      f4 R0, R1, R2, R3, bv;
      if (act) {
        R0 = *(const f4*)(R + (size_t)(l4 + 0) * (MM * MM) + (size_t)s * MM);
        R1 = *(const f4*)(R + (size_t)(l4 + 1) * (MM * MM) + (size_t)s * MM);
        R2 = *(const f4*)(R + (size_t)(l4 + 2) * (MM * MM) + (size_t)s * MM);
        R3 = *(const f4*)(R + (size_t)(l4 + 3) * (MM * MM) + (size_t)s * MM);
        bv = *(const f4*)(bias + scol);
      }
#pragma unroll
      for (int ti = 0; ti < QT; ++ti) {
        const int t = q * QT + ti;
        if (act) {
          const float* t1p = t1s + t * TPAD + l4;
          f4 a0 = *(const f4*)(t1p);
          f4 a1 = *(const f4*)(t1p + MM);
          f4 a2 = *(const f4*)(t1p + 2 * MM);
          f4 a3 = *(const f4*)(t1p + 3 * MM);
          f4 o;
          o.x = fmaf(a3.x, R0.w, fmaf(a2.x, R0.z, fmaf(a1.x, R0.y, fmaf(a0.x, R0.x, bv.x))));
          o.y = fmaf(a3.y, R1.w, fmaf(a2.y, R1.z, fmaf(a1.y, R1.y, fmaf(a0.y, R1.x, bv.y))));
          o.z = fmaf(a3.z, R2.w, fmaf(a2.z, R2.z, fmaf(a1.z, R2.y, fmaf(a0.z, R2.x, bv.z))));
          o.w = fmaf(a3.w, R3.w, fmaf(a2.w, R3.z, fmaf(a1.w, R3.y, fmaf(a0.w, R3.x, bv.w))));
          *(f4*)(out + (tb + t) * OUT_D + scol) = o;
        }
      }
    }
    // ---- A(q+1): overlaps with B(q)'s store drain ----
    if (q < TT / QT - 1) {
      const float* xq = axls + (q + 1) * QT * XROW;
      float*       tq = at1w + (q + 1) * QT * TPAD;
      if (liq == 0) dotA<5>(xq, aL0, tq, ap4m);
      else          dotA<4>(xq, aL0, tq, ap4m);
      __syncthreads();                             // quarter q+1 t1 ready
    }
  }
}

extern "C" void kernel_launch(void* const* d_in, const int* in_sizes, int n_in,
                              void* d_out, int out_size, void* d_ws, size_t ws_size,
                              hipStream_t stream) {
  const float* x    = (const float*)d_in[0];
  const float* L    = (const float*)d_in[1];
  const float* R    = (const float*)d_in[2];
  const float* bias = (const float*)d_in[3];
  float* out = (float*)d_out;

  const int ntok = in_sizes[0] / IN_D;     // 16384
  monarch_pipe<<<ntok / TT, NTH, 0, stream>>>(x, L, R, bias, out);
}

// Round 17
// 101.433 us; speedup vs baseline: 1.5065x; 1.5065x over previous
//
#include <hip/hip_runtime.h>

// MonarchLinear: x[16384,256] fp32, L[68,68,68], R[68,68,68], bias[4608] -> out[16384,4608] fp32.
//   t1[b,r,l] = sum_p x[b, r*68+p] * L[r,l,p]           (r<4; r==3 only p<52 valid)
//   out[b, s*68+l] = sum_{r<4} t1[b,r,l] * R[l,s,r] + bias[s*68+l]
//
// Round 17. r16's regression was the tell: 4x-ing B's R loads cost +61us ->
// each R load is a 64-DISTINCT-LINE scatter (lane m varies l4; l is R's outer
// dim, 18.5KB stride) costing ~150cy serialized TA each. B carries 21 such
// instrs/thread ~= 20-25us/CU that neither drains nor overlaps — the gap
// between the 46.6us write roofline and r13's 91us. Fix: one-time pack kernel
// (1 block, 102KB ws) gathers each thread's per-j operands into Rp[j][q][tid]
// (f4, lane-contiguous) -> B's loads become 1KB coalesced instrs. Structure
// otherwise = r15: stage -> A (p4-outer, wave-uniform L) -> B, 4 blocks/CU.

typedef float f4 __attribute__((ext_vector_type(4)));

namespace {
constexpr int MM    = 68;
constexpr int IN_D  = 256;
constexpr int OUT_D = 4608;
constexpr int TT    = 16;              // tokens per block
constexpr int NTH   = 256;
constexpr int NJ    = 5;
constexpr int XROW  = IN_D + 4;        // 260 floats: x row stride in LDS
constexpr int TPAD  = 4 * MM + 4;      // 276 floats: t1 row stride
constexpr int RPF4  = NJ * 5 * NTH;    // 6400 f4 = 102,400 B in ws
}

// ---------------- one-time R/bias repack: Rp[j][q][tid] (q=4 -> bias) ----------------
__global__ __launch_bounds__(NTH, 1)
void pack_R(const float* __restrict__ R, const float* __restrict__ bias,
            f4* __restrict__ Rp)
{
  const int tid = threadIdx.x;
  const int g   = tid / 17;
  const int m   = tid - g * 17;
  const int l4  = 4 * m;
#pragma unroll 1
  for (int j = 0; j < NJ; ++j) {
    const int s = g + 15 * j;
    const bool act = (tid < 255) && (s < MM) && (s < MM - 1 || m < 13);
    f4 v[5];
#pragma unroll
    for (int q = 0; q < 5; ++q) v[q] = f4{0.f, 0.f, 0.f, 0.f};
    if (act) {
#pragma unroll
      for (int q = 0; q < 4; ++q)
        v[q] = *(const f4*)(R + (size_t)(l4 + q) * (MM * MM) + (size_t)s * MM);
      v[4] = *(const f4*)(bias + s * MM + l4);
    }
#pragma unroll
    for (int q = 0; q < 5; ++q)
      Rp[(j * 5 + q) * NTH + tid] = v[q];          // lane-contiguous layout
  }
}

// ---- phase-A dot worker: p4 outer, li inner; batched independent loads ----
template <int P4M>
__device__ __forceinline__ void phaseA(const float* __restrict__ xls,
                                       const float* __restrict__ Lrow0,
                                       float* __restrict__ t1w)
{
  float acc[17];
#pragma unroll
  for (int li = 0; li < 17; ++li) acc[li] = 0.f;

#pragma unroll 1
  for (int p4 = 0; p4 < P4M; ++p4) {
    f4 xv = *(const f4*)(xls + 4 * p4);            // LDS
    f4 Lv[17];
#pragma unroll
    for (int li = 0; li < 17; ++li)                // wave: 4 distinct addrs/instr
      Lv[li] = *(const f4*)(Lrow0 + (size_t)li * MM + 4 * p4);
#pragma unroll
    for (int li = 0; li < 17; ++li) {
      acc[li] = fmaf(xv.x, Lv[li].x, acc[li]);
      acc[li] = fmaf(xv.y, Lv[li].y, acc[li]);
      acc[li] = fmaf(xv.z, Lv[li].z, acc[li]);
      acc[li] = fmaf(xv.w, Lv[li].w, acc[li]);
    }
  }
#pragma unroll
  for (int li = 0; li < 17; ++li) t1w[li] = acc[li];
}

template <bool USE_RP>
__global__ __launch_bounds__(NTH, 4)     // VGPR cap 128; 4 blocks/CU
void monarch_fused(const float* __restrict__ x, const float* __restrict__ L,
                   const float* __restrict__ R, const float* __restrict__ bias,
                   const f4* __restrict__ Rp, float* __restrict__ out)
{
  __shared__ float xs[TT * XROW];        // 16,640 B
  __shared__ float t1s[TT * TPAD];       // 17,664 B  (34.3 KB total)
  const int tid = threadIdx.x;
  const long tb = (long)blockIdx.x * TT;

  // ---- stage x -> LDS ----
#pragma unroll
  for (int k = 0; k < (TT * IN_D / 4) / NTH; ++k) {
    int i   = k * NTH + tid;
    int tok = i >> 6;
    int pos = i & 63;
    *(f4*)(&xs[tok * XROW + 4 * pos]) = *(const f4*)(x + (tb + tok) * IN_D + 4 * pos);
  }
  __syncthreads();

  // ---- phase A ----
  {
    const int tok = tid & 15;
    const int seg = tid >> 4;
    const int r   = seg >> 2;
    const int lq  = seg & 3;
    const float* xls   = &xs[tok * XROW + r * MM];
    const float* Lrow0 = L + (size_t)(r * MM + lq * 17) * MM;
    float*       t1w   = &t1s[tok * TPAD + r * MM + lq * 17];
    if (r < 3) phaseA<17>(xls, Lrow0, t1w);
    else       phaseA<13>(xls, Lrow0, t1w);
  }
  __syncthreads();

  // ---- phase B ----
  {
    const int g  = tid / 17;
    const int m  = tid - g * 17;
    const int l4 = 4 * m;

#pragma unroll 1
    for (int j = 0; j < NJ; ++j) {
      const int s = g + 15 * j;
      const bool act = (tid < 255) && (s < MM) && (s < MM - 1 || m < 13);
      const int scol = s * MM + l4;
      f4 R0, R1, R2, R3, bv;
      if (USE_RP) {                       // 1KB lane-contiguous coalesced loads
        R0 = Rp[(j * 5 + 0) * NTH + tid];
        R1 = Rp[(j * 5 + 1) * NTH + tid];
        R2 = Rp[(j * 5 + 2) * NTH + tid];
        R3 = Rp[(j * 5 + 3) * NTH + tid];
        bv = Rp[(j * 5 + 4) * NTH + tid];
      } else if (act) {                   // fallback: 64-line scatters
        R0 = *(const f4*)(R + (size_t)(l4 + 0) * (MM * MM) + (size_t)s * MM);
        R1 = *(const f4*)(R + (size_t)(l4 + 1) * (MM * MM) + (size_t)s * MM);
        R2 = *(const f4*)(R + (size_t)(l4 + 2) * (MM * MM) + (size_t)s * MM);
        R3 = *(const f4*)(R + (size_t)(l4 + 3) * (MM * MM) + (size_t)s * MM);
        bv = *(const f4*)(bias + scol);
      }
#pragma unroll 2
      for (int t = 0; t < TT; ++t) {
        if (act) {
          const float* t1p = t1s + t * TPAD + l4;
          f4 a0 = *(const f4*)(t1p);
          f4 a1 = *(const f4*)(t1p + MM);
          f4 a2 = *(const f4*)(t1p + 2 * MM);
          f4 a3 = *(const f4*)(t1p + 3 * MM);
          f4 o;
          o.x = fmaf(a3.x, R0.w, fmaf(a2.x, R0.z, fmaf(a1.x, R0.y, fmaf(a0.x, R0.x, bv.x))));
          o.y = fmaf(a3.y, R1.w, fmaf(a2.y, R1.z, fmaf(a1.y, R1.y, fmaf(a0.y, R1.x, bv.y))));
          o.z = fmaf(a3.z, R2.w, fmaf(a2.z, R2.z, fmaf(a1.z, R2.y, fmaf(a0.z, R2.x, bv.z))));
          o.w = fmaf(a3.w, R3.w, fmaf(a2.w, R3.z, fmaf(a1.w, R3.y, fmaf(a0.w, R3.x, bv.w))));
          *(f4*)(out + (tb + t) * OUT_D + scol) = o;
        }
      }
    }
  }
}

extern "C" void kernel_launch(void* const* d_in, const int* in_sizes, int n_in,
                              void* d_out, int out_size, void* d_ws, size_t ws_size,
                              hipStream_t stream) {
  const float* x    = (const float*)d_in[0];
  const float* L    = (const float*)d_in[1];
  const float* R    = (const float*)d_in[2];
  const float* bias = (const float*)d_in[3];
  float* out = (float*)d_out;

  const int ntok = in_sizes[0] / IN_D;     // 16384

  if (ws_size >= (size_t)RPF4 * sizeof(f4)) {
    f4* Rp = (f4*)d_ws;
    pack_R<<<1, NTH, 0, stream>>>(R, bias, Rp);
    monarch_fused<true><<<ntok / TT, NTH, 0, stream>>>(x, L, R, bias, Rp, out);
  } else {
    monarch_fused<false><<<ntok / TT, NTH, 0, stream>>>(x, L, R, bias, nullptr, out);
  }
}

// Round 18
// 100.970 us; speedup vs baseline: 1.5134x; 1.0046x over previous
//
#include <hip/hip_runtime.h>

// MonarchLinear: x[16384,256] fp32, L[68,68,68], R[68,68,68], bias[4608] -> out[16384,4608] fp32.
//   t1[b,r,l] = sum_p x[b, r*68+p] * L[r,l,p]           (r<4; r==3 only p<52 valid)
//   out[b, s*68+l] = sum_{r<4} t1[b,r,l] * R[l,s,r] + bias[s*68+l]
//
// Round 18: TA-visit model (calibrated on r16's +60instr<->+61us) says the kernel
// is address-unit bound: A's L loads = 18.5k line-visits/CU (289 instr x 16 waves
// x 4 scattered 16B addrs). This round halves A's visits: lanes = (tok|p4q), so
// each L-load instr reads 64B CONTIGUOUS (1-2 lines), partials reduced over the
// p4q lane bits via shfl_xor(16/32). B = r13 verbatim. No extra dispatch.

typedef float f4 __attribute__((ext_vector_type(4)));

namespace {
constexpr int MM    = 68;
constexpr int IN_D  = 256;
constexpr int OUT_D = 4608;
constexpr int TT    = 16;              // tokens per block
constexpr int NTH   = 256;
constexpr int NJ    = 5;
constexpr int XROW  = IN_D + 4;        // 260 floats: x row stride in LDS
constexpr int TPAD  = 4 * MM + 4;      // 276 floats: t1 row stride
}

// One phase-A pass: seg (r,lq) wave-uniform; lane = (tok | q). Lane q covers
// p4 = {4s+q, s<FS} + tail p4=4FS (q==0 only, via zeroed xvt). FS=4 (r<3), 3 (r==3).
template <int FS>
__device__ __forceinline__ void aPass(const float* __restrict__ xrow,
                                      const float* __restrict__ Lbase,
                                      float* __restrict__ t1w, int q)
{
  f4 xvr[FS];
#pragma unroll
  for (int s = 0; s < FS; ++s)
    xvr[s] = *(const f4*)(xrow + 4 * (4 * s + q));
  f4 xvt = *(const f4*)(xrow + 4 * (4 * FS));      // broadcast-ish (16 toks)
  if (q != 0) xvt = f4{0.f, 0.f, 0.f, 0.f};        // tail belongs to q==0 only

  float acc[17];
#pragma unroll
  for (int li = 0; li < 17; ++li) acc[li] = 0.f;

#pragma unroll 2
  for (int li = 0; li < 17; ++li) {
    const float* Lrow = Lbase + (size_t)li * MM;
    float a = acc[li];
#pragma unroll
    for (int s = 0; s < FS; ++s) {                 // 64B-contiguous across q lanes
      f4 Lv = *(const f4*)(Lrow + 4 * (4 * s + q));
      a = fmaf(xvr[s].x, Lv.x, a);
      a = fmaf(xvr[s].y, Lv.y, a);
      a = fmaf(xvr[s].z, Lv.z, a);
      a = fmaf(xvr[s].w, Lv.w, a);
    }
    f4 Lvt = *(const f4*)(Lrow + 4 * (4 * FS));    // single-line broadcast
    a = fmaf(xvt.x, Lvt.x, a);
    a = fmaf(xvt.y, Lvt.y, a);
    a = fmaf(xvt.z, Lvt.z, a);
    a = fmaf(xvt.w, Lvt.w, a);
    acc[li] = a;
  }

  // reduce partials over q (lane bits 4,5); q==0 lanes write
#pragma unroll
  for (int li = 0; li < 17; ++li) {
    float v = acc[li];
    v += __shfl_xor(v, 16, 64);
    v += __shfl_xor(v, 32, 64);
    if (q == 0) t1w[li] = v;
  }
}

__global__ __launch_bounds__(NTH, 4)     // VGPR cap 128; 4 blocks/CU
void monarch_fused(const float* __restrict__ x, const float* __restrict__ L,
                   const float* __restrict__ R, const float* __restrict__ bias,
                   float* __restrict__ out)
{
  __shared__ float xs[TT * XROW];        // 16,640 B
  __shared__ float t1s[TT * TPAD];       // 17,664 B  (34.3 KB total)
  const int tid = threadIdx.x;
  const long tb = (long)blockIdx.x * TT;

  // ---- stage x -> LDS: 16 rows x 64 f4, coalesced ----
#pragma unroll
  for (int k = 0; k < (TT * IN_D / 4) / NTH; ++k) {
    int i   = k * NTH + tid;
    int tok = i >> 6;
    int pos = i & 63;
    *(f4*)(&xs[tok * XROW + 4 * pos]) = *(const f4*)(x + (tb + tok) * IN_D + 4 * pos);
  }
  __syncthreads();

  // ---- phase A: lanes (tok|q), wave = lq, loop sg = r ----
  {
    const int lane = tid & 63;
    const int tok  = lane & 15;
    const int q    = lane >> 4;          // 0..3 p4-quarter
    const int lq   = tid >> 6;           // wave id

#pragma unroll 1
    for (int r = 0; r < 4; ++r) {        // uniform across ALL waves
      const float* xrow  = &xs[tok * XROW + r * MM];
      const float* Lbase = L + (size_t)(r * MM + lq * 17) * MM;
      float*       t1w   = &t1s[tok * TPAD + r * MM + lq * 17];
      if (r < 3) aPass<4>(xrow, Lbase, t1w, q);
      else       aPass<3>(xrow, Lbase, t1w, q);    // p<52: 3 full steps + tail@12
    }
  }
  __syncthreads();

  // ---- phase B: r13 verbatim (proven) ----
  {
    const int g  = tid / 17;
    const int m  = tid - g * 17;
    const int l4 = 4 * m;

#pragma unroll 1                         // j rolled: 20 hoisted regs per iter
    for (int j = 0; j < NJ; ++j) {
      const int s = g + 15 * j;
      // tid==255 (g==15,m==0) duplicates (g=0,j+1); s==67 row has only 52 cols (m<13)
      const bool act = (tid < 255) && (s < MM) && (s < MM - 1 || m < 13);
      const int scol = s * MM + l4;
      f4 R0, R1, R2, R3, bv;
      if (act) {
        R0 = *(const f4*)(R + (size_t)(l4 + 0) * (MM * MM) + (size_t)s * MM);
        R1 = *(const f4*)(R + (size_t)(l4 + 1) * (MM * MM) + (size_t)s * MM);
        R2 = *(const f4*)(R + (size_t)(l4 + 2) * (MM * MM) + (size_t)s * MM);
        R3 = *(const f4*)(R + (size_t)(l4 + 3) * (MM * MM) + (size_t)s * MM);
        bv = *(const f4*)(bias + scol);
      }
#pragma unroll 2
      for (int t = 0; t < TT; ++t) {
        if (act) {
          const float* t1p = t1s + t * TPAD + l4;
          f4 a0 = *(const f4*)(t1p);
          f4 a1 = *(const f4*)(t1p + MM);
          f4 a2 = *(const f4*)(t1p + 2 * MM);
          f4 a3 = *(const f4*)(t1p + 3 * MM);
          f4 o;
          o.x = fmaf(a3.x, R0.w, fmaf(a2.x, R0.z, fmaf(a1.x, R0.y, fmaf(a0.x, R0.x, bv.x))));
          o.y = fmaf(a3.y, R1.w, fmaf(a2.y, R1.z, fmaf(a1.y, R1.y, fmaf(a0.y, R1.x, bv.y))));
          o.z = fmaf(a3.z, R2.w, fmaf(a2.z, R2.z, fmaf(a1.z, R2.y, fmaf(a0.z, R2.x, bv.z))));
          o.w = fmaf(a3.w, R3.w, fmaf(a2.w, R3.z, fmaf(a1.w, R3.y, fmaf(a0.w, R3.x, bv.w))));
          *(f4*)(out + (tb + t) * OUT_D + scol) = o;
        }
      }
    }
  }
}

extern "C" void kernel_launch(void* const* d_in, const int* in_sizes, int n_in,
                              void* d_out, int out_size, void* d_ws, size_t ws_size,
                              hipStream_t stream) {
  const float* x    = (const float*)d_in[0];
  const float* L    = (const float*)d_in[1];
  const float* R    = (const float*)d_in[2];
  const float* bias = (const float*)d_in[3];
  float* out = (float*)d_out;

  const int ntok = in_sizes[0] / IN_D;     // 16384
  monarch_fused<<<ntok / TT, NTH, 0, stream>>>(x, L, R, bias, out);
}